// Round 1
// baseline (1075.356 us; speedup 1.0000x reference)
//
#include <hip/hip_runtime.h>

#define NN 100000
#define EE 1600000
#define HH 128
#define BB 8192

// ---------------- CSR build ----------------

__global__ void hist_kernel(const int* __restrict__ dst, int* __restrict__ hist) {
    int e = blockIdx.x * blockDim.x + threadIdx.x;
    if (e < EE) atomicAdd(&hist[dst[e]], 1);
}

__global__ void dinv_kernel(const int* __restrict__ hist, float* __restrict__ dinv) {
    int i = blockIdx.x * blockDim.x + threadIdx.x;
    if (i < NN) dinv[i] = rsqrtf((float)hist[i] + 1.0f);  // +1 self loop; deg>=1 always
}

__global__ __launch_bounds__(1024) void scan_kernel(const int* __restrict__ hist,
        int* __restrict__ offs, int* __restrict__ cursor) {
    __shared__ int sums[1024];
    const int tid = threadIdx.x;
    const int chunk = (NN + 1023) / 1024;  // 98
    int s0 = tid * chunk;
    int s1 = s0 + chunk; if (s1 > NN) s1 = NN;
    if (s0 > NN) s0 = NN;
    int s = 0;
    for (int i = s0; i < s1; ++i) s += hist[i];
    sums[tid] = s;
    __syncthreads();
    for (int d = 1; d < 1024; d <<= 1) {
        int v = (tid >= d) ? sums[tid - d] : 0;
        __syncthreads();
        sums[tid] += v;
        __syncthreads();
    }
    int base = (tid > 0) ? sums[tid - 1] : 0;
    for (int i = s0; i < s1; ++i) {
        offs[i] = base;
        cursor[i] = base;
        base += hist[i];
    }
    if (tid == 1023) offs[NN] = sums[1023];
}

__global__ void fill_kernel(const int* __restrict__ src, const int* __restrict__ dst,
        const float* __restrict__ dinv, int* __restrict__ cursor,
        int* __restrict__ esrc, float* __restrict__ enorm) {
    int e = blockIdx.x * blockDim.x + threadIdx.x;
    if (e >= EE) return;
    int s = src[e], d = dst[e];
    int p = atomicAdd(&cursor[d], 1);
    esrc[p] = s;
    enorm[p] = dinv[s] * dinv[d];
}

// ---------------- fp32 GEMM [M,128] x [128,128] ----------------
// 256 threads/block, 64 rows/block. Thread (tcol=tid&31, trow=tid>>5)
// computes 8 rows x 4 cols (cols tcol+32i -> conflict-free LDS reads,
// coalesced stores). A-tile and W-chunk staged in 48 KB LDS.

__global__ __launch_bounds__(256) void gemm128(const float* __restrict__ A,
        const float* __restrict__ W, const float* __restrict__ bias,
        float* __restrict__ C, int M, int relu) {
    __shared__ float Ws[64 * 128];  // 32 KB: K-chunk of W
    __shared__ float As[64 * 64];   // 16 KB: A tile chunk
    const int tid = threadIdx.x;
    const int row0 = blockIdx.x * 64;
    const int tcol = tid & 31, trow = tid >> 5;

    float acc[8][4];
#pragma unroll
    for (int r = 0; r < 8; ++r)
#pragma unroll
        for (int i = 0; i < 4; ++i) acc[r][i] = 0.f;

    for (int kc = 0; kc < 128; kc += 64) {
        __syncthreads();  // protect LDS from previous iteration's readers
        // load W chunk: rows kc..kc+63, 2048 float4
#pragma unroll
        for (int i = 0; i < 8; ++i) {
            int p = tid + 256 * i;
            ((float4*)Ws)[p] = ((const float4*)W)[kc * 32 + p];
        }
        // load A tile chunk: 64 rows x 64 cols, 1024 float4
#pragma unroll
        for (int i = 0; i < 4; ++i) {
            int p = tid + 256 * i;
            int r = p >> 4, c4 = p & 15;
            int gr = row0 + r;
            float4 v = make_float4(0.f, 0.f, 0.f, 0.f);
            if (gr < M) v = *(const float4*)&A[(size_t)gr * HH + kc + c4 * 4];
            ((float4*)As)[p] = v;
        }
        __syncthreads();

#pragma unroll
        for (int k4 = 0; k4 < 16; ++k4) {
            float4 a[8];
#pragma unroll
            for (int r = 0; r < 8; ++r)
                a[r] = *(const float4*)&As[(trow * 8 + r) * 64 + k4 * 4];
#pragma unroll
            for (int j = 0; j < 4; ++j) {
                float w[4];
#pragma unroll
                for (int i = 0; i < 4; ++i)
                    w[i] = Ws[(k4 * 4 + j) * 128 + tcol + 32 * i];
#pragma unroll
                for (int r = 0; r < 8; ++r) {
                    float av = (j == 0) ? a[r].x : (j == 1) ? a[r].y : (j == 2) ? a[r].z : a[r].w;
#pragma unroll
                    for (int i = 0; i < 4; ++i) acc[r][i] += av * w[i];
                }
            }
        }
    }

    float bv[4] = {0.f, 0.f, 0.f, 0.f};
    if (bias) {
#pragma unroll
        for (int i = 0; i < 4; ++i) bv[i] = bias[tcol + 32 * i];
    }
#pragma unroll
    for (int r = 0; r < 8; ++r) {
        int gr = row0 + trow * 8 + r;
        if (gr < M) {
#pragma unroll
            for (int i = 0; i < 4; ++i) {
                float v = acc[r][i] + bv[i];
                if (relu) v = fmaxf(v, 0.f);
                C[(size_t)gr * HH + tcol + 32 * i] = v;
            }
        }
    }
}

// ---------------- aggregation: out[i] = sum_in-edges t[src]*norm + t[i]*dinv[i]^2 + b ----------------
// one wave per node, float2 per lane (64 lanes x 2 = 128 features)

__global__ __launch_bounds__(256) void agg_kernel(const float* __restrict__ t,
        float* __restrict__ out, const int* __restrict__ offs,
        const int* __restrict__ esrc, const float* __restrict__ enorm,
        const float* __restrict__ dinv, const float* __restrict__ bias, int relu) {
    const int wave = threadIdx.x >> 6;
    const int lane = threadIdx.x & 63;
    const int node = blockIdx.x * 4 + wave;
    if (node >= NN) return;
    const int f = lane * 2;

    float di = dinv[node];
    float2 sv = *(const float2*)&t[(size_t)node * HH + f];
    float ax = sv.x * di * di;
    float ay = sv.y * di * di;

    int e = offs[node];
    const int e1 = offs[node + 1];
    for (; e + 4 <= e1; e += 4) {
        int s0 = esrc[e], s1 = esrc[e + 1], s2 = esrc[e + 2], s3 = esrc[e + 3];
        float n0 = enorm[e], n1 = enorm[e + 1], n2 = enorm[e + 2], n3 = enorm[e + 3];
        float2 v0 = *(const float2*)&t[(size_t)s0 * HH + f];
        float2 v1 = *(const float2*)&t[(size_t)s1 * HH + f];
        float2 v2 = *(const float2*)&t[(size_t)s2 * HH + f];
        float2 v3 = *(const float2*)&t[(size_t)s3 * HH + f];
        ax += v0.x * n0; ay += v0.y * n0;
        ax += v1.x * n1; ay += v1.y * n1;
        ax += v2.x * n2; ay += v2.y * n2;
        ax += v3.x * n3; ay += v3.y * n3;
    }
    for (; e < e1; ++e) {
        int s = esrc[e];
        float nm = enorm[e];
        float2 v = *(const float2*)&t[(size_t)s * HH + f];
        ax += v.x * nm; ay += v.y * nm;
    }

    float2 b = make_float2(0.f, 0.f);
    if (bias) b = *(const float2*)&bias[f];
    ax += b.x; ay += b.y;
    if (relu) { ax = fmaxf(ax, 0.f); ay = fmaxf(ay, 0.f); }
    *(float2*)&out[(size_t)node * HH + f] = make_float2(ax, ay);
}

// ---------------- link head ----------------

__global__ __launch_bounds__(256) void link_kernel(const float* __restrict__ h,
        const int* __restrict__ roots, float* __restrict__ linkb) {
    const int wave = threadIdx.x >> 6;
    const int lane = threadIdx.x & 63;
    const int b = blockIdx.x * 4 + wave;
    if (b >= BB) return;
    const int f = lane * 2;
    int r0 = roots[b * 2], r1 = roots[b * 2 + 1];
    float2 u = *(const float2*)&h[(size_t)r0 * HH + f];
    float2 v = *(const float2*)&h[(size_t)r1 * HH + f];
    *(float2*)&linkb[(size_t)b * HH + f] = make_float2(u.x * v.x, u.y * v.y);
}

__global__ __launch_bounds__(256) void logits_kernel(const float* __restrict__ g,
        const float* __restrict__ P2, const float* __restrict__ pb2,
        float* __restrict__ out) {
    const int wave = threadIdx.x >> 6;
    const int lane = threadIdx.x & 63;
    const int b = blockIdx.x * 4 + wave;
    if (b >= BB) return;
    const int f = lane * 2;
    float2 gv = *(const float2*)&g[(size_t)b * HH + f];
    float2 pv = *(const float2*)&P2[f];
    float s = gv.x * pv.x + gv.y * pv.y;
    for (int off = 32; off > 0; off >>= 1) s += __shfl_down(s, off);
    if (lane == 0) out[b] = s + pb2[0];
}

// ---------------- launcher ----------------

extern "C" void kernel_launch(void* const* d_in, const int* in_sizes, int n_in,
                              void* d_out, int out_size, void* d_ws, size_t ws_size,
                              hipStream_t stream) {
    const float* x   = (const float*)d_in[0];
    const int*   ei  = (const int*)d_in[1];
    const int* roots = (const int*)d_in[2];
    const float* W1  = (const float*)d_in[3];
    const float* b1  = (const float*)d_in[4];
    const float* W2  = (const float*)d_in[5];
    const float* b2  = (const float*)d_in[6];
    const float* W3  = (const float*)d_in[7];
    const float* b3  = (const float*)d_in[8];
    const float* P1  = (const float*)d_in[9];
    const float* pb1 = (const float*)d_in[10];
    const float* P2  = (const float*)d_in[11];
    const float* pb2 = (const float*)d_in[12];
    float* out = (float*)d_out;
    (void)in_sizes; (void)n_in; (void)out_size; (void)ws_size;

    char* ws = (char*)d_ws;
    size_t woff = 0;
    auto alloc = [&](size_t bytes) {
        void* p = ws + woff;
        woff += (bytes + 255) & ~(size_t)255;
        return p;
    };
    int*   hist   = (int*)  alloc((size_t)NN * 4);
    float* dinv   = (float*)alloc((size_t)NN * 4);
    int*   offs   = (int*)  alloc((size_t)(NN + 1) * 4);
    int*   cursor = (int*)  alloc((size_t)NN * 4);
    int*   esrc   = (int*)  alloc((size_t)EE * 4);
    float* enorm  = (float*)alloc((size_t)EE * 4);
    float* bufA   = (float*)alloc((size_t)NN * HH * 4);
    float* bufB   = (float*)alloc((size_t)NN * HH * 4);
    float* linkb  = (float*)alloc((size_t)BB * HH * 4);
    float* gout   = (float*)alloc((size_t)BB * HH * 4);

    const int* e_src = ei;        // edge_index[0]
    const int* e_dst = ei + EE;   // edge_index[1]

    hipMemsetAsync(hist, 0, (size_t)NN * 4, stream);
    hist_kernel<<<(EE + 255) / 256, 256, 0, stream>>>(e_dst, hist);
    dinv_kernel<<<(NN + 255) / 256, 256, 0, stream>>>(hist, dinv);
    scan_kernel<<<1, 1024, 0, stream>>>(hist, offs, cursor);
    fill_kernel<<<(EE + 255) / 256, 256, 0, stream>>>(e_src, e_dst, dinv, cursor, esrc, enorm);

    // layer 1: t = x@W1 ; h1 = relu(agg(t) + b1)
    gemm128<<<(NN + 63) / 64, 256, 0, stream>>>(x, W1, nullptr, bufA, NN, 0);
    agg_kernel<<<(NN + 3) / 4, 256, 0, stream>>>(bufA, bufB, offs, esrc, enorm, dinv, b1, 1);
    // layer 2
    gemm128<<<(NN + 63) / 64, 256, 0, stream>>>(bufB, W2, nullptr, bufA, NN, 0);
    agg_kernel<<<(NN + 3) / 4, 256, 0, stream>>>(bufA, bufB, offs, esrc, enorm, dinv, b2, 1);
    // layer 3 (no relu)
    gemm128<<<(NN + 63) / 64, 256, 0, stream>>>(bufB, W3, nullptr, bufA, NN, 0);
    agg_kernel<<<(NN + 3) / 4, 256, 0, stream>>>(bufA, bufB, offs, esrc, enorm, dinv, b3, 0);

    // head
    link_kernel<<<(BB + 3) / 4, 256, 0, stream>>>(bufB, roots, linkb);
    gemm128<<<(BB + 63) / 64, 256, 0, stream>>>(linkb, P1, pb1, gout, BB, 1);
    logits_kernel<<<(BB + 3) / 4, 256, 0, stream>>>(gout, P2, pb2, out);
}

// Round 5
// 852.841 us; speedup vs baseline: 1.2609x; 1.2609x over previous
//
#include <hip/hip_runtime.h>

#define NN 100000
#define EE 1600000
#define HH 128
#define BB 8192
#define SCAN_NBLK ((NN + 1023) / 1024)   // 98

// ---------------- CSR build ----------------

__global__ void hist_kernel(const int* __restrict__ dst, int* __restrict__ hist) {
    int e = blockIdx.x * blockDim.x + threadIdx.x;
    if (e < EE) atomicAdd(&hist[dst[e]], 1);
}

__global__ void dinv_kernel(const int* __restrict__ hist, float* __restrict__ dinv) {
    int i = blockIdx.x * blockDim.x + threadIdx.x;
    if (i < NN) dinv[i] = rsqrtf((float)hist[i] + 1.0f);  // +1 self loop; deg>=1 always
}

// hierarchical exclusive scan of hist -> offs/cursor (3 kernels, replaces the
// 233 us single-block scan: 1 CU + serial 98-elem loops was latency-bound)

__global__ __launch_bounds__(1024) void scan_partial_kernel(const int* __restrict__ hist,
        int* __restrict__ bsum) {
    __shared__ int red[1024];
    int i = blockIdx.x * 1024 + threadIdx.x;
    int v = (i < NN) ? hist[i] : 0;
    red[threadIdx.x] = v;
    __syncthreads();
    for (int d = 512; d > 0; d >>= 1) {
        if (threadIdx.x < d) red[threadIdx.x] += red[threadIdx.x + d];
        __syncthreads();
    }
    if (threadIdx.x == 0) bsum[blockIdx.x] = red[0];
}

__global__ void scan_sums_kernel(const int* __restrict__ bsum, int* __restrict__ bbase) {
    int acc = 0;
    for (int b = 0; b < SCAN_NBLK; ++b) { bbase[b] = acc; acc += bsum[b]; }
    bbase[SCAN_NBLK] = acc;
}

__global__ __launch_bounds__(1024) void scan_offs_kernel(const int* __restrict__ hist,
        const int* __restrict__ bbase, int* __restrict__ offs, int* __restrict__ cursor) {
    __shared__ int sc[1024];
    int i = blockIdx.x * 1024 + threadIdx.x;
    int v = (i < NN) ? hist[i] : 0;
    sc[threadIdx.x] = v;
    __syncthreads();
    for (int d = 1; d < 1024; d <<= 1) {
        int t = (threadIdx.x >= d) ? sc[threadIdx.x - d] : 0;
        __syncthreads();
        sc[threadIdx.x] += t;
        __syncthreads();
    }
    if (i < NN) {
        int excl = bbase[blockIdx.x] + sc[threadIdx.x] - v;
        offs[i] = excl;
        cursor[i] = excl;
        if (i == NN - 1) offs[NN] = excl + v;
    }
}

__global__ void fill_kernel(const int* __restrict__ src, const int* __restrict__ dst,
        const float* __restrict__ dinv, int* __restrict__ cursor,
        int* __restrict__ esrc, float* __restrict__ enorm) {
    int e = blockIdx.x * blockDim.x + threadIdx.x;
    if (e >= EE) return;
    int s = src[e], d = dst[e];
    int p = atomicAdd(&cursor[d], 1);
    esrc[p] = s;
    enorm[p] = dinv[s] * dinv[d];
}

// ---------------- fp32 GEMM [M,128] x [128,128] ----------------
// 256 threads/block, 64 rows/block. Thread (tcol=tid&31, trow=tid>>5)
// computes 8 rows x 4 cols (cols tcol+32i -> conflict-free LDS reads,
// coalesced stores). A-tile and W-chunk staged in 48 KB LDS.

__global__ __launch_bounds__(256) void gemm128(const float* __restrict__ A,
        const float* __restrict__ W, const float* __restrict__ bias,
        float* __restrict__ C, int M, int relu) {
    __shared__ float Ws[64 * 128];  // 32 KB: K-chunk of W
    __shared__ float As[64 * 64];   // 16 KB: A tile chunk
    const int tid = threadIdx.x;
    const int row0 = blockIdx.x * 64;
    const int tcol = tid & 31, trow = tid >> 5;

    float acc[8][4];
#pragma unroll
    for (int r = 0; r < 8; ++r)
#pragma unroll
        for (int i = 0; i < 4; ++i) acc[r][i] = 0.f;

    for (int kc = 0; kc < 128; kc += 64) {
        __syncthreads();  // protect LDS from previous iteration's readers
        // load W chunk: rows kc..kc+63, 2048 float4
#pragma unroll
        for (int i = 0; i < 8; ++i) {
            int p = tid + 256 * i;
            ((float4*)Ws)[p] = ((const float4*)W)[kc * 32 + p];
        }
        // load A tile chunk: 64 rows x 64 cols, 1024 float4
#pragma unroll
        for (int i = 0; i < 4; ++i) {
            int p = tid + 256 * i;
            int r = p >> 4, c4 = p & 15;
            int gr = row0 + r;
            float4 v = make_float4(0.f, 0.f, 0.f, 0.f);
            if (gr < M) v = *(const float4*)&A[(size_t)gr * HH + kc + c4 * 4];
            ((float4*)As)[p] = v;
        }
        __syncthreads();

#pragma unroll
        for (int k4 = 0; k4 < 16; ++k4) {
            float4 a[8];
#pragma unroll
            for (int r = 0; r < 8; ++r)
                a[r] = *(const float4*)&As[(trow * 8 + r) * 64 + k4 * 4];
#pragma unroll
            for (int j = 0; j < 4; ++j) {
                float w[4];
#pragma unroll
                for (int i = 0; i < 4; ++i)
                    w[i] = Ws[(k4 * 4 + j) * 128 + tcol + 32 * i];
#pragma unroll
                for (int r = 0; r < 8; ++r) {
                    float av = (j == 0) ? a[r].x : (j == 1) ? a[r].y : (j == 2) ? a[r].z : a[r].w;
#pragma unroll
                    for (int i = 0; i < 4; ++i) acc[r][i] += av * w[i];
                }
            }
        }
    }

    float bv[4] = {0.f, 0.f, 0.f, 0.f};
    if (bias) {
#pragma unroll
        for (int i = 0; i < 4; ++i) bv[i] = bias[tcol + 32 * i];
    }
#pragma unroll
    for (int r = 0; r < 8; ++r) {
        int gr = row0 + trow * 8 + r;
        if (gr < M) {
#pragma unroll
            for (int i = 0; i < 4; ++i) {
                float v = acc[r][i] + bv[i];
                if (relu) v = fmaxf(v, 0.f);
                C[(size_t)gr * HH + tcol + 32 * i] = v;
            }
        }
    }
}

// ---------------- aggregation: out[i] = sum_in-edges t[src]*norm + t[i]*dinv[i]^2 + b ----------------
// one wave per node, float2 per lane (64 lanes x 2 = 128 features)

__global__ __launch_bounds__(256) void agg_kernel(const float* __restrict__ t,
        float* __restrict__ out, const int* __restrict__ offs,
        const int* __restrict__ esrc, const float* __restrict__ enorm,
        const float* __restrict__ dinv, const float* __restrict__ bias, int relu) {
    const int wave = threadIdx.x >> 6;
    const int lane = threadIdx.x & 63;
    const int node = blockIdx.x * 4 + wave;
    if (node >= NN) return;
    const int f = lane * 2;

    float di = dinv[node];
    float2 sv = *(const float2*)&t[(size_t)node * HH + f];
    float ax = sv.x * di * di;
    float ay = sv.y * di * di;

    int e = offs[node];
    const int e1 = offs[node + 1];
    for (; e + 4 <= e1; e += 4) {
        int s0 = esrc[e], s1 = esrc[e + 1], s2 = esrc[e + 2], s3 = esrc[e + 3];
        float n0 = enorm[e], n1 = enorm[e + 1], n2 = enorm[e + 2], n3 = enorm[e + 3];
        float2 v0 = *(const float2*)&t[(size_t)s0 * HH + f];
        float2 v1 = *(const float2*)&t[(size_t)s1 * HH + f];
        float2 v2 = *(const float2*)&t[(size_t)s2 * HH + f];
        float2 v3 = *(const float2*)&t[(size_t)s3 * HH + f];
        ax += v0.x * n0; ay += v0.y * n0;
        ax += v1.x * n1; ay += v1.y * n1;
        ax += v2.x * n2; ay += v2.y * n2;
        ax += v3.x * n3; ay += v3.y * n3;
    }
    for (; e < e1; ++e) {
        int s = esrc[e];
        float nm = enorm[e];
        float2 v = *(const float2*)&t[(size_t)s * HH + f];
        ax += v.x * nm; ay += v.y * nm;
    }

    float2 b = make_float2(0.f, 0.f);
    if (bias) b = *(const float2*)&bias[f];
    ax += b.x; ay += b.y;
    if (relu) { ax = fmaxf(ax, 0.f); ay = fmaxf(ay, 0.f); }
    *(float2*)&out[(size_t)node * HH + f] = make_float2(ax, ay);
}

// ---------------- link head ----------------

__global__ __launch_bounds__(256) void link_kernel(const float* __restrict__ h,
        const int* __restrict__ roots, float* __restrict__ linkb) {
    const int wave = threadIdx.x >> 6;
    const int lane = threadIdx.x & 63;
    const int b = blockIdx.x * 4 + wave;
    if (b >= BB) return;
    const int f = lane * 2;
    int r0 = roots[b * 2], r1 = roots[b * 2 + 1];
    float2 u = *(const float2*)&h[(size_t)r0 * HH + f];
    float2 v = *(const float2*)&h[(size_t)r1 * HH + f];
    *(float2*)&linkb[(size_t)b * HH + f] = make_float2(u.x * v.x, u.y * v.y);
}

__global__ __launch_bounds__(256) void logits_kernel(const float* __restrict__ g,
        const float* __restrict__ P2, const float* __restrict__ pb2,
        float* __restrict__ out) {
    const int wave = threadIdx.x >> 6;
    const int lane = threadIdx.x & 63;
    const int b = blockIdx.x * 4 + wave;
    if (b >= BB) return;
    const int f = lane * 2;
    float2 gv = *(const float2*)&g[(size_t)b * HH + f];
    float2 pv = *(const float2*)&P2[f];
    float s = gv.x * pv.x + gv.y * pv.y;
    for (int off = 32; off > 0; off >>= 1) s += __shfl_down(s, off);
    if (lane == 0) out[b] = s + pb2[0];
}

// ---------------- launcher ----------------

extern "C" void kernel_launch(void* const* d_in, const int* in_sizes, int n_in,
                              void* d_out, int out_size, void* d_ws, size_t ws_size,
                              hipStream_t stream) {
    const float* x   = (const float*)d_in[0];
    const int*   ei  = (const int*)d_in[1];
    const int* roots = (const int*)d_in[2];
    const float* W1  = (const float*)d_in[3];
    const float* b1  = (const float*)d_in[4];
    const float* W2  = (const float*)d_in[5];
    const float* b2  = (const float*)d_in[6];
    const float* W3  = (const float*)d_in[7];
    const float* b3  = (const float*)d_in[8];
    const float* P1  = (const float*)d_in[9];
    const float* pb1 = (const float*)d_in[10];
    const float* P2  = (const float*)d_in[11];
    const float* pb2 = (const float*)d_in[12];
    float* out = (float*)d_out;
    (void)in_sizes; (void)n_in; (void)out_size; (void)ws_size;

    char* ws = (char*)d_ws;
    size_t woff = 0;
    auto alloc = [&](size_t bytes) {
        void* p = ws + woff;
        woff += (bytes + 255) & ~(size_t)255;
        return p;
    };
    int*   hist   = (int*)  alloc((size_t)NN * 4);
    float* dinv   = (float*)alloc((size_t)NN * 4);
    int*   offs   = (int*)  alloc((size_t)(NN + 1) * 4);
    int*   cursor = (int*)  alloc((size_t)NN * 4);
    int*   bsum   = (int*)  alloc((size_t)(SCAN_NBLK + 1) * 4);
    int*   bbase  = (int*)  alloc((size_t)(SCAN_NBLK + 1) * 4);
    int*   esrc   = (int*)  alloc((size_t)EE * 4);
    float* enorm  = (float*)alloc((size_t)EE * 4);
    float* bufA   = (float*)alloc((size_t)NN * HH * 4);
    float* bufB   = (float*)alloc((size_t)NN * HH * 4);
    float* linkb  = (float*)alloc((size_t)BB * HH * 4);
    float* gout   = (float*)alloc((size_t)BB * HH * 4);

    const int* e_src = ei;        // edge_index[0]
    const int* e_dst = ei + EE;   // edge_index[1]

    hipMemsetAsync(hist, 0, (size_t)NN * 4, stream);
    hist_kernel<<<(EE + 255) / 256, 256, 0, stream>>>(e_dst, hist);
    dinv_kernel<<<(NN + 255) / 256, 256, 0, stream>>>(hist, dinv);
    scan_partial_kernel<<<SCAN_NBLK, 1024, 0, stream>>>(hist, bsum);
    scan_sums_kernel<<<1, 1, 0, stream>>>(bsum, bbase);
    scan_offs_kernel<<<SCAN_NBLK, 1024, 0, stream>>>(hist, bbase, offs, cursor);
    fill_kernel<<<(EE + 255) / 256, 256, 0, stream>>>(e_src, e_dst, dinv, cursor, esrc, enorm);

    // layer 1: t = x@W1 ; h1 = relu(agg(t) + b1)
    gemm128<<<(NN + 63) / 64, 256, 0, stream>>>(x, W1, nullptr, bufA, NN, 0);
    agg_kernel<<<(NN + 3) / 4, 256, 0, stream>>>(bufA, bufB, offs, esrc, enorm, dinv, b1, 1);
    // layer 2
    gemm128<<<(NN + 63) / 64, 256, 0, stream>>>(bufB, W2, nullptr, bufA, NN, 0);
    agg_kernel<<<(NN + 3) / 4, 256, 0, stream>>>(bufA, bufB, offs, esrc, enorm, dinv, b2, 1);
    // layer 3 (no relu)
    gemm128<<<(NN + 63) / 64, 256, 0, stream>>>(bufB, W3, nullptr, bufA, NN, 0);
    agg_kernel<<<(NN + 3) / 4, 256, 0, stream>>>(bufA, bufB, offs, esrc, enorm, dinv, b3, 0);

    // head
    link_kernel<<<(BB + 3) / 4, 256, 0, stream>>>(bufB, roots, linkb);
    gemm128<<<(BB + 63) / 64, 256, 0, stream>>>(linkb, P1, pb1, gout, BB, 1);
    logits_kernel<<<(BB + 3) / 4, 256, 0, stream>>>(gout, P2, pb2, out);
}